// Round 8
// baseline (102.956 us; speedup 1.0000x reference)
//
#include <hip/hip_runtime.h>
#include <math.h>

// A3C batch-1 forward, R7: 3 hops + parallel epilogue + comm-line prewarm.
//
// Model after R1-R6: bench floor 84us is harness poison-fills/restores; our
// kernel ~18us is (a) per-stage straggler maxima and (b) cold 0xAA-poisoned
// communication lines paying a storm-era miss at hop time. R7: every block
// touches (discarded atomic load) the exact ws lines it will send/recv, at
// t0, so hop-time accesses are L3 hits; 3 hops total; partial-head epilogue
// parallel across G blocks; PT slots = 1 line per G block.
//
// Layout (61 blocks, TPB=256), dispatch order = load size:
//   G: blk 0..31   4 LSTM cells/blk (16 gate rows) + full w4 (redundant,
//                  L3-shared). Early: g0=W_hh@hx+biases. recv H3 -> h4 ->
//                  gates -> LSTM(4) -> 7 head partials -> send PT line.
//   A: blk 32..35  h1, 64 rows/blk, 4 lanes/row -> send H1
//   B: blk 36..51  h2, 16 rows/blk, 16 lanes/row (recv H1) -> send H2
//   C: blk 52..59  h3, 16 rows/blk, 16 lanes/row (recv H2) -> send H3
//   R: blk 60      recv 32x7 partials (stride-8 lines), reduce, softsign, out

#define NB   61
#define TPB  256
#define MAGIC 0x3A3C5A17u

#define H1_OFF 0      // 256 pairs (16 lines)
#define H2_OFF 256    // 256 pairs (16 lines)
#define H3_OFF 512    // 128 pairs (8 lines)
#define PT_OFF 640    // 32 lines: G block g owns pairs [g*8 .. g*8+7], head h at +h

__device__ __forceinline__ float lrelu(float v) { return v > 0.f ? v : 0.1f * v; }
__device__ __forceinline__ float sigm(float v)  { return 1.f / (1.f + __expf(-v)); }
__device__ __forceinline__ float dot4(float4 a, float4 b) {
    return a.x * b.x + a.y * b.y + a.z * b.z + a.w * b.w;
}

__device__ __forceinline__ void send(unsigned long long* p, float v) {
    unsigned lo = __float_as_uint(v);
    unsigned long long pk = (unsigned long long)lo |
                            ((unsigned long long)(lo ^ MAGIC) << 32);
    __hip_atomic_store(p, pk, __ATOMIC_RELAXED, __HIP_MEMORY_SCOPE_AGENT);
}
__device__ __forceinline__ float recv(unsigned long long* p) {
    unsigned long long pk =
        __hip_atomic_load(p, __ATOMIC_RELAXED, __HIP_MEMORY_SCOPE_AGENT);
    unsigned lo = (unsigned)pk, hi = (unsigned)(pk >> 32);
    if ((lo ^ MAGIC) == hi) return __uint_as_float(lo);
    __builtin_amdgcn_s_sleep(2);
    for (;;) {
        pk = __hip_atomic_load(p, __ATOMIC_RELAXED, __HIP_MEMORY_SCOPE_AGENT);
        lo = (unsigned)pk; hi = (unsigned)(pk >> 32);
        if ((lo ^ MAGIC) == hi) return __uint_as_float(lo);
        __builtin_amdgcn_s_sleep(8);
    }
}
// Pull a comm line toward L3/L1 now; result consumed so it can't be DCE'd.
__device__ __forceinline__ void touch(unsigned long long* p) {
    unsigned long long v =
        __hip_atomic_load(p, __ATOMIC_RELAXED, __HIP_MEMORY_SCOPE_AGENT);
    asm volatile("" :: "v"(v));
}

__global__ __launch_bounds__(TPB, 1) void a3c_fwd(
    const float* __restrict__ x, const float* __restrict__ hx, const float* __restrict__ cx,
    const float* __restrict__ w1, const float* __restrict__ b1,
    const float* __restrict__ w2, const float* __restrict__ b2,
    const float* __restrict__ w3, const float* __restrict__ b3,
    const float* __restrict__ w4, const float* __restrict__ b4,
    const float* __restrict__ w_ih, const float* __restrict__ b_ih,
    const float* __restrict__ w_hh, const float* __restrict__ b_hh,
    const float* __restrict__ w_critic, const float* __restrict__ b_critic,
    const float* __restrict__ w_actor, const float* __restrict__ b_actor,
    const float* __restrict__ w_actor2, const float* __restrict__ b_actor2,
    float* __restrict__ out, unsigned long long* __restrict__ wsp)
{
    const int blk = blockIdx.x, tid = threadIdx.x;

    if (blk < 32) {
        // -------- Team G: 4 LSTM cells/blk + redundant h4 + head partials ----
        const int g  = blk;
        const int gc = g * 4;
        const int r  = tid >> 4, p = tid & 15;       // 16 gate rows x 16 lanes
        const int gate = r >> 2, cell = r & 3;
        const int grow = gate * 128 + gc + cell;
        const int r4 = tid >> 1, p4 = tid & 1;       // h4: 128 rows x 2 x 64

        // t0: prewarm comm lines this block reads/writes
        if (tid < 8)       touch(wsp + H3_OFF + tid * 16);   // recv set
        else if (tid == 8) touch(wsp + PT_OFF + g * 8);      // send line

        __shared__ __align__(16) float hx_s[128];
        __shared__ __align__(16) float h3_s[128];
        __shared__ __align__(16) float h4_s[128];
        __shared__ __align__(16) float g_s[16];
        __shared__ __align__(16) float hn_s[4];
        __shared__ __align__(16) float hw_s[28];
        __shared__ __align__(16) float hb_s[8];

        float4 ah0, ah1;
        {
            const float4* wp = (const float4*)(w_hh + grow * 128 + p * 8);
            ah0 = wp[0]; ah1 = wp[1];
        }
        float4 a4[16];
        {
            const float4* wp = (const float4*)(w4 + r4 * 128 + p4 * 64);
            #pragma unroll
            for (int j = 0; j < 16; ++j) a4[j] = wp[j];
        }
        float4 ai0, ai1;
        {
            const float4* wp = (const float4*)(w_ih + grow * 128 + p * 8);
            ai0 = wp[0]; ai1 = wp[1];
        }
        const float bsum = b_ih[grow] + b_hh[grow];
        const float bb4  = b4[r4];
        float cxv = (tid < 4) ? cx[gc + tid] : 0.f;

        if (tid < 128) hx_s[tid] = hx[tid];
        if (tid < 28) {
            int o = tid >> 2, c = tid & 3;
            float v;
            if (o == 0)      v = w_critic[gc + c];
            else if (o < 4)  v = w_actor [(o - 1) * 128 + gc + c];
            else             v = w_actor2[(o - 4) * 128 + gc + c];
            hw_s[tid] = v;
        }
        if (g == 0 && tid == 0) {
            hb_s[0] = b_critic[0];
            hb_s[1] = b_actor[0];  hb_s[2] = b_actor[1];  hb_s[3] = b_actor[2];
            hb_s[4] = b_actor2[0]; hb_s[5] = b_actor2[1]; hb_s[6] = b_actor2[2];
        }
        __syncthreads();

        // g0 = W_hh @ hx + b_ih + b_hh (off critical path)
        float g0;
        {
            const float4* hp = (const float4*)(hx_s + p * 8);
            float s = dot4(ah0, hp[0]) + dot4(ah1, hp[1]);
            s += __shfl_xor(s, 1); s += __shfl_xor(s, 2);
            s += __shfl_xor(s, 4); s += __shfl_xor(s, 8);
            g0 = s + bsum;
        }

        if (tid < 128) h3_s[tid] = recv(wsp + H3_OFF + tid);
        __syncthreads();

        { // h4 = lrelu(W4 @ h3 + b4), block-local
            const float4* hp = (const float4*)(h3_s + p4 * 64);
            float s = 0.f;
            #pragma unroll
            for (int j = 0; j < 16; ++j) s += dot4(a4[j], hp[j]);
            s += __shfl_xor(s, 1);
            if (p4 == 0) h4_s[r4] = lrelu(s + bb4);
        }
        __syncthreads();

        { // 16 gate rows
            const float4* hp = (const float4*)(h4_s + p * 8);
            float s = dot4(ai0, hp[0]) + dot4(ai1, hp[1]);
            s += __shfl_xor(s, 1); s += __shfl_xor(s, 2);
            s += __shfl_xor(s, 4); s += __shfl_xor(s, 8);
            if (p == 0) g_s[r] = g0 + s;   // r = gate*4 + cell
        }
        __syncthreads();

        if (tid < 4) {   // LSTM elementwise, 4 cells
            float ig = g_s[tid];
            float fg = g_s[4 + tid];
            float gg = g_s[8 + tid];
            float og = g_s[12 + tid];
            float c  = sigm(fg) * cxv + sigm(ig) * tanhf(gg);
            hn_s[tid] = sigm(og) * tanhf(c);
        }
        __syncthreads();

        if (tid < 7) {   // 7 head partials over this block's 4 cells
            const float* wc = hw_s + tid * 4;
            float s = wc[0] * hn_s[0] + wc[1] * hn_s[1]
                    + wc[2] * hn_s[2] + wc[3] * hn_s[3];
            if (g == 0) s += hb_s[tid];
            send(wsp + PT_OFF + g * 8 + tid, s);
        }
        return;
    }

    if (blk < 36) {
        // -------- Team A: h1 (64 rows/blk, 4 lanes/row) --------
        const int row = (blk - 32) * 64 + (tid >> 2), sub = tid & 3;
        if (tid < 4) touch(wsp + H1_OFF + (blk - 32) * 64 + tid * 16);  // send lines

        float a[8];
        #pragma unroll
        for (int j = 0; j < 8; ++j) {
            int c = sub * 8 + j;
            a[j] = (c < 29) ? w1[row * 29 + c] : 0.f;
        }
        const float bb1 = b1[row];

        __shared__ __align__(16) float x_s[32];
        if (tid < 32) x_s[tid] = (tid < 29) ? x[tid] : 0.f;
        __syncthreads();

        const float* xp = x_s + sub * 8;
        float s = 0.f;
        #pragma unroll
        for (int j = 0; j < 8; ++j) s += a[j] * xp[j];
        s += __shfl_xor(s, 1); s += __shfl_xor(s, 2);
        if (sub == 0) send(wsp + H1_OFF + row, lrelu(s + bb1));
        return;
    }

    if (blk < 52) {
        // -------- Team B: h2 (16 rows/blk, 16 lanes/row) --------
        const int b = blk - 36;
        const int row = b * 16 + (tid >> 4), p = tid & 15;
        if (tid < 16)       touch(wsp + H1_OFF + tid * 16);   // recv set
        else if (tid == 16) touch(wsp + H2_OFF + b * 16);     // send line

        float4 a2[4];
        {
            const float4* wp = (const float4*)(w2 + row * 256 + p * 16);
            #pragma unroll
            for (int j = 0; j < 4; ++j) a2[j] = wp[j];
        }
        const float bb2 = b2[row];

        __shared__ __align__(16) float h1_s[256];
        h1_s[tid] = recv(wsp + H1_OFF + tid);
        __syncthreads();

        const float4* hp = (const float4*)(h1_s + p * 16);
        float s = 0.f;
        #pragma unroll
        for (int j = 0; j < 4; ++j) s += dot4(a2[j], hp[j]);
        s += __shfl_xor(s, 1); s += __shfl_xor(s, 2);
        s += __shfl_xor(s, 4); s += __shfl_xor(s, 8);
        if (p == 0) send(wsp + H2_OFF + row, lrelu(s + bb2));
        return;
    }

    if (blk < 60) {
        // -------- Team C: h3 (16 rows/blk, 16 lanes/row) --------
        const int b = blk - 52;
        const int row = b * 16 + (tid >> 4), p = tid & 15;
        if (tid < 16)       touch(wsp + H2_OFF + tid * 16);   // recv set
        else if (tid == 16) touch(wsp + H3_OFF + b * 16);     // send line

        float4 a3[4];
        {
            const float4* wp = (const float4*)(w3 + row * 256 + p * 16);
            #pragma unroll
            for (int j = 0; j < 4; ++j) a3[j] = wp[j];
        }
        const float bb3 = b3[row];

        __shared__ __align__(16) float h2_s[256];
        h2_s[tid] = recv(wsp + H2_OFF + tid);
        __syncthreads();

        const float4* hp = (const float4*)(h2_s + p * 16);
        float s = 0.f;
        #pragma unroll
        for (int j = 0; j < 4; ++j) s += dot4(a3[j], hp[j]);
        s += __shfl_xor(s, 1); s += __shfl_xor(s, 2);
        s += __shfl_xor(s, 4); s += __shfl_xor(s, 8);
        if (p == 0) send(wsp + H3_OFF + row, lrelu(s + bb3));
        return;
    }

    // -------- Reducer (blk 60) --------
    {
        if (tid < 32) touch(wsp + PT_OFF + tid * 8);
        __shared__ __align__(16) float ps[224];
        const int g = tid >> 3, h = tid & 7;
        if (h < 7) ps[h * 32 + g] = recv(wsp + PT_OFF + g * 8 + h);
        __syncthreads();
        if (tid < 7) {
            const float* row = ps + tid * 32;
            float s = 0.f;
            #pragma unroll
            for (int j = 0; j < 32; ++j) s += row[j];
            if (tid >= 1 && tid <= 3) s = s / (1.f + fabsf(s));
            out[tid] = s;
        }
    }
}

extern "C" void kernel_launch(void* const* d_in, const int* in_sizes, int n_in,
                              void* d_out, int out_size, void* d_ws, size_t ws_size,
                              hipStream_t stream) {
    const float* x        = (const float*)d_in[0];
    const float* hx       = (const float*)d_in[1];
    const float* cx       = (const float*)d_in[2];
    const float* w1       = (const float*)d_in[3];
    const float* b1       = (const float*)d_in[4];
    const float* w2       = (const float*)d_in[5];
    const float* b2       = (const float*)d_in[6];
    const float* w3       = (const float*)d_in[7];
    const float* b3       = (const float*)d_in[8];
    const float* w4       = (const float*)d_in[9];
    const float* b4       = (const float*)d_in[10];
    const float* w_ih     = (const float*)d_in[11];
    const float* b_ih     = (const float*)d_in[12];
    const float* w_hh     = (const float*)d_in[13];
    const float* b_hh     = (const float*)d_in[14];
    const float* w_critic = (const float*)d_in[15];
    const float* b_critic = (const float*)d_in[16];
    const float* w_actor  = (const float*)d_in[17];
    const float* b_actor  = (const float*)d_in[18];
    const float* w_actor2 = (const float*)d_in[19];
    const float* b_actor2 = (const float*)d_in[20];
    float* out = (float*)d_out;
    unsigned long long* wsp = (unsigned long long*)d_ws;

    a3c_fwd<<<NB, TPB, 0, stream>>>(x, hx, cx, w1, b1, w2, b2, w3, b3, w4, b4,
                                    w_ih, b_ih, w_hh, b_hh,
                                    w_critic, b_critic, w_actor, b_actor,
                                    w_actor2, b_actor2, out, wsp);
}

// Round 9
// 102.883 us; speedup vs baseline: 1.0007x; 1.0007x over previous
//
#include <hip/hip_runtime.h>
#include <math.h>

// A3C batch-1 forward, R8: pipeline-ordered dispatch + balanced per-block
// fetch + 4 warm hops.
//
// Constraint set this round satisfies simultaneously (no prior round did):
//  (a) stage teams dispatched in pipeline order (B->C->D->G->R),
//  (b) every block's weight fetch <= 46 KB (~<4us at the measured ~12 GB/s
//      per-CU cold-read rate) and issued at t0, earliest-needed first,
//  (c) 4 hops, all via self-validating (val, val^MAGIC) relaxed agent-scope
//      8B atomics with t0 prewarm (lines warm by hop time).
//
// Teams (TPB=256, NB=41):
//   B: blk 0..15  h1 redundant (W1 30KB, needed first) + 16 h2 rows
//                 (W2 slice 16KB) -> send H2
//   C: blk 16..19 32 h3 rows (W3 slice 32KB); recv H2 -> send H3
//   D: blk 20..23 32 h4 rows (W4 slice 16KB); recv H3 -> send H4
//   G: blk 24..39 8 LSTM cells = 32 gate rows (W_ih+W_hh slices 32KB);
//                 g0 = W_hh@hx early; recv H4 -> gates -> LSTM(8 cells) ->
//                 7 head partials -> send PT line
//   R: blk 40     recv 16x7 partials -> reduce -> softsign -> out

#define NB   41
#define TPB  256
#define MAGIC 0x3A3C5A17u

#define H2_OFF 0      // 256 pairs (16 lines)
#define H3_OFF 256    // 128 pairs (8 lines)
#define H4_OFF 384    // 128 pairs (8 lines)
#define PT_OFF 512    // 16 lines, G block g owns pairs [g*8 .. g*8+7]

__device__ __forceinline__ float lrelu(float v) { return v > 0.f ? v : 0.1f * v; }
__device__ __forceinline__ float sigm(float v)  { return 1.f / (1.f + __expf(-v)); }
__device__ __forceinline__ float dot4(float4 a, float4 b) {
    return a.x * b.x + a.y * b.y + a.z * b.z + a.w * b.w;
}

__device__ __forceinline__ void send(unsigned long long* p, float v) {
    unsigned lo = __float_as_uint(v);
    unsigned long long pk = (unsigned long long)lo |
                            ((unsigned long long)(lo ^ MAGIC) << 32);
    __hip_atomic_store(p, pk, __ATOMIC_RELAXED, __HIP_MEMORY_SCOPE_AGENT);
}
__device__ __forceinline__ float recv(unsigned long long* p) {
    unsigned long long pk =
        __hip_atomic_load(p, __ATOMIC_RELAXED, __HIP_MEMORY_SCOPE_AGENT);
    unsigned lo = (unsigned)pk, hi = (unsigned)(pk >> 32);
    if ((lo ^ MAGIC) == hi) return __uint_as_float(lo);
    __builtin_amdgcn_s_sleep(2);
    for (;;) {
        pk = __hip_atomic_load(p, __ATOMIC_RELAXED, __HIP_MEMORY_SCOPE_AGENT);
        lo = (unsigned)pk; hi = (unsigned)(pk >> 32);
        if ((lo ^ MAGIC) == hi) return __uint_as_float(lo);
        __builtin_amdgcn_s_sleep(8);
    }
}
__device__ __forceinline__ void touch(unsigned long long* p) {
    unsigned long long v =
        __hip_atomic_load(p, __ATOMIC_RELAXED, __HIP_MEMORY_SCOPE_AGENT);
    asm volatile("" :: "v"(v));
}

__global__ __launch_bounds__(TPB, 1) void a3c_fwd(
    const float* __restrict__ x, const float* __restrict__ hx, const float* __restrict__ cx,
    const float* __restrict__ w1, const float* __restrict__ b1,
    const float* __restrict__ w2, const float* __restrict__ b2,
    const float* __restrict__ w3, const float* __restrict__ b3,
    const float* __restrict__ w4, const float* __restrict__ b4,
    const float* __restrict__ w_ih, const float* __restrict__ b_ih,
    const float* __restrict__ w_hh, const float* __restrict__ b_hh,
    const float* __restrict__ w_critic, const float* __restrict__ b_critic,
    const float* __restrict__ w_actor, const float* __restrict__ b_actor,
    const float* __restrict__ w_actor2, const float* __restrict__ b_actor2,
    float* __restrict__ out, unsigned long long* __restrict__ wsp)
{
    const int blk = blockIdx.x, tid = threadIdx.x;

    if (blk < 16) {
        // ---- Team B: h1 (redundant, W1 first) + 16 h2 rows ----
        const int b = blk;
        if (tid == 0) touch(wsp + H2_OFF + b * 16);   // send line (16 pairs = 2 lines)
        if (tid == 1) touch(wsp + H2_OFF + b * 16 + 8);

        // W1 row for this thread (needed first)
        float a1[29];
        {
            const float* w1r = w1 + tid * 29;
            #pragma unroll
            for (int j = 0; j < 29; ++j) a1[j] = w1r[j];
        }
        const float bb1 = b1[tid];

        // W2 slice: row = b*16 + (tid>>4), lane p = tid&15 covers 16 floats
        const int r2 = b * 16 + (tid >> 4), p2 = tid & 15;
        float4 a2[4];
        {
            const float4* wp = (const float4*)(w2 + r2 * 256 + p2 * 16);
            #pragma unroll
            for (int j = 0; j < 4; ++j) a2[j] = wp[j];
        }
        const float bb2 = b2[r2];

        __shared__ __align__(16) float x_s[32];
        __shared__ __align__(16) float h1_s[256];
        if (tid < 32) x_s[tid] = (tid < 29) ? x[tid] : 0.f;
        __syncthreads();

        { // h1: 1 row per thread
            float s = 0.f;
            #pragma unroll
            for (int j = 0; j < 29; ++j) s += a1[j] * x_s[j];
            h1_s[tid] = lrelu(s + bb1);
        }
        __syncthreads();

        { // h2 row slice
            const float4* hp = (const float4*)(h1_s + p2 * 16);
            float s = 0.f;
            #pragma unroll
            for (int j = 0; j < 4; ++j) s += dot4(a2[j], hp[j]);
            s += __shfl_xor(s, 1); s += __shfl_xor(s, 2);
            s += __shfl_xor(s, 4); s += __shfl_xor(s, 8);
            if (p2 == 0) send(wsp + H2_OFF + r2, lrelu(s + bb2));
        }
        return;
    }

    if (blk < 20) {
        // ---- Team C: 32 h3 rows/blk ----
        const int c = blk - 16;
        if (tid < 16)       touch(wsp + H2_OFF + tid * 16);  // recv set
        else if (tid < 20)  touch(wsp + H3_OFF + c * 32 + (tid - 16) * 8); // send

        const int r3 = c * 32 + (tid >> 3), p3 = tid & 7;    // 32 floats/lane
        float4 a3[8];
        {
            const float4* wp = (const float4*)(w3 + r3 * 256 + p3 * 32);
            #pragma unroll
            for (int j = 0; j < 8; ++j) a3[j] = wp[j];
        }
        const float bb3 = b3[r3];

        __shared__ __align__(16) float h2_s[256];
        h2_s[tid] = recv(wsp + H2_OFF + tid);
        __syncthreads();

        const float4* hp = (const float4*)(h2_s + p3 * 32);
        float s = 0.f;
        #pragma unroll
        for (int j = 0; j < 8; ++j) s += dot4(a3[j], hp[j]);
        s += __shfl_xor(s, 1); s += __shfl_xor(s, 2); s += __shfl_xor(s, 4);
        if (p3 == 0) send(wsp + H3_OFF + r3, lrelu(s + bb3));
        return;
    }

    if (blk < 24) {
        // ---- Team D: 32 h4 rows/blk ----
        const int d = blk - 20;
        if (tid < 8)        touch(wsp + H3_OFF + tid * 16);  // recv set
        else if (tid < 12)  touch(wsp + H4_OFF + d * 32 + (tid - 8) * 8); // send

        const int r4 = d * 32 + (tid >> 3), p4 = tid & 7;    // 16 floats/lane
        float4 a4[4];
        {
            const float4* wp = (const float4*)(w4 + r4 * 128 + p4 * 16);
            #pragma unroll
            for (int j = 0; j < 4; ++j) a4[j] = wp[j];
        }
        const float bb4 = b4[r4];

        __shared__ __align__(16) float h3_s[128];
        if (tid < 128) h3_s[tid] = recv(wsp + H3_OFF + tid);
        __syncthreads();

        const float4* hp = (const float4*)(h3_s + p4 * 16);
        float s = 0.f;
        #pragma unroll
        for (int j = 0; j < 4; ++j) s += dot4(a4[j], hp[j]);
        s += __shfl_xor(s, 1); s += __shfl_xor(s, 2); s += __shfl_xor(s, 4);
        if (p4 == 0) send(wsp + H4_OFF + r4, lrelu(s + bb4));
        return;
    }

    if (blk < 40) {
        // ---- Team G: 8 LSTM cells/blk (32 gate rows) + head partials ----
        const int g = blk - 24;
        if (tid < 8)       touch(wsp + H4_OFF + tid * 16);   // recv set
        else if (tid == 8) touch(wsp + PT_OFF + g * 8);      // send line

        const int r = tid >> 3, p = tid & 7;     // 32 rows x 8 lanes x 16 floats
        const int gate = r >> 3, cell = r & 7;
        const int grow = gate * 128 + g * 8 + cell;

        float4 ah[4];
        {
            const float4* wp = (const float4*)(w_hh + grow * 128 + p * 16);
            #pragma unroll
            for (int j = 0; j < 4; ++j) ah[j] = wp[j];
        }
        float4 ai[4];
        {
            const float4* wp = (const float4*)(w_ih + grow * 128 + p * 16);
            #pragma unroll
            for (int j = 0; j < 4; ++j) ai[j] = wp[j];
        }
        const float bsum = b_ih[grow] + b_hh[grow];

        __shared__ __align__(16) float hx_s[128];
        __shared__ __align__(16) float h4_s[128];
        __shared__ __align__(16) float g_s[32];
        __shared__ __align__(16) float hn_s[8];
        __shared__ __align__(16) float hw_s[56];
        __shared__ __align__(16) float hb_s[8];

        if (tid < 128) hx_s[tid] = hx[tid];
        float cxv = (tid < 8) ? cx[g * 8 + tid] : 0.f;
        if (tid < 56) {                       // head weight slices: 7 heads x 8 cells
            int o = tid >> 3, c = tid & 7;
            float v;
            if (o == 0)      v = w_critic[g * 8 + c];
            else if (o < 4)  v = w_actor [(o - 1) * 128 + g * 8 + c];
            else             v = w_actor2[(o - 4) * 128 + g * 8 + c];
            hw_s[tid] = v;
        }
        if (g == 0 && tid == 0) {
            hb_s[0] = b_critic[0];
            hb_s[1] = b_actor[0];  hb_s[2] = b_actor[1];  hb_s[3] = b_actor[2];
            hb_s[4] = b_actor2[0]; hb_s[5] = b_actor2[1]; hb_s[6] = b_actor2[2];
        }
        __syncthreads();

        // g0 = W_hh @ hx + biases (off critical path)
        float g0;
        {
            const float4* hp = (const float4*)(hx_s + p * 16);
            float s = 0.f;
            #pragma unroll
            for (int j = 0; j < 4; ++j) s += dot4(ah[j], hp[j]);
            s += __shfl_xor(s, 1); s += __shfl_xor(s, 2); s += __shfl_xor(s, 4);
            g0 = s + bsum;
        }

        if (tid < 128) h4_s[tid] = recv(wsp + H4_OFF + tid);
        __syncthreads();

        { // gates for 32 rows
            const float4* hp = (const float4*)(h4_s + p * 16);
            float s = 0.f;
            #pragma unroll
            for (int j = 0; j < 4; ++j) s += dot4(ai[j], hp[j]);
            s += __shfl_xor(s, 1); s += __shfl_xor(s, 2); s += __shfl_xor(s, 4);
            if (p == 0) g_s[r] = g0 + s;   // r = gate*8 + cell
        }
        __syncthreads();

        if (tid < 8) {   // LSTM elementwise, 8 cells
            float ig = g_s[tid];
            float fg = g_s[8 + tid];
            float gg = g_s[16 + tid];
            float og = g_s[24 + tid];
            float c  = sigm(fg) * cxv + sigm(ig) * tanhf(gg);
            hn_s[tid] = sigm(og) * tanhf(c);
        }
        __syncthreads();

        if (tid < 7) {   // 7 head partials over this block's 8 cells
            const float* wc = hw_s + tid * 8;
            float s = 0.f;
            #pragma unroll
            for (int j = 0; j < 8; ++j) s += wc[j] * hn_s[j];
            if (g == 0) s += hb_s[tid];
            send(wsp + PT_OFF + g * 8 + tid, s);
        }
        return;
    }

    // ---- Reducer (blk 40): 16x7 partials -> 7 outputs ----
    {
        if (tid < 16) touch(wsp + PT_OFF + tid * 8);
        __shared__ __align__(16) float ps[112];
        const int g = tid >> 3, h = tid & 7;
        if (tid < 128 && h < 7) ps[h * 16 + g] = recv(wsp + PT_OFF + g * 8 + h);
        __syncthreads();
        if (tid < 7) {
            const float* row = ps + tid * 16;
            float s = 0.f;
            #pragma unroll
            for (int j = 0; j < 16; ++j) s += row[j];
            if (tid >= 1 && tid <= 3) s = s / (1.f + fabsf(s));
            out[tid] = s;
        }
    }
}

extern "C" void kernel_launch(void* const* d_in, const int* in_sizes, int n_in,
                              void* d_out, int out_size, void* d_ws, size_t ws_size,
                              hipStream_t stream) {
    const float* x        = (const float*)d_in[0];
    const float* hx       = (const float*)d_in[1];
    const float* cx       = (const float*)d_in[2];
    const float* w1       = (const float*)d_in[3];
    const float* b1       = (const float*)d_in[4];
    const float* w2       = (const float*)d_in[5];
    const float* b2       = (const float*)d_in[6];
    const float* w3       = (const float*)d_in[7];
    const float* b3       = (const float*)d_in[8];
    const float* w4       = (const float*)d_in[9];
    const float* b4       = (const float*)d_in[10];
    const float* w_ih     = (const float*)d_in[11];
    const float* b_ih     = (const float*)d_in[12];
    const float* w_hh     = (const float*)d_in[13];
    const float* b_hh     = (const float*)d_in[14];
    const float* w_critic = (const float*)d_in[15];
    const float* b_critic = (const float*)d_in[16];
    const float* w_actor  = (const float*)d_in[17];
    const float* b_actor  = (const float*)d_in[18];
    const float* w_actor2 = (const float*)d_in[19];
    const float* b_actor2 = (const float*)d_in[20];
    float* out = (float*)d_out;
    unsigned long long* wsp = (unsigned long long*)d_ws;

    a3c_fwd<<<NB, TPB, 0, stream>>>(x, hx, cx, w1, b1, w2, b2, w3, b3, w4, b4,
                                    w_ih, b_ih, w_hh, b_hh,
                                    w_critic, b_critic, w_actor, b_actor,
                                    w_actor2, b_actor2, out, wsp);
}

// Round 10
// 100.723 us; speedup vs baseline: 1.0222x; 1.0214x over previous
//
#include <hip/hip_runtime.h>
#include <math.h>

// A3C batch-1 forward, R9: R8 pipeline + 8-producer final stage + folded
// reducer (32 blocks total).
//
// Consolidated model (R0-R8): bench = ~84us harness floor (256MiB poison
// fills + input restores) + kernel ~18us = ~2us launch + ~5us post-fill
// HBM write-drain storm (structure-insensitive) + ~10us pipeline. Remaining
// levers are tail/straggler terms:
//  - G team 16 -> 8 blocks (final hop gates kernel retirement; halve its
//    producer straggler set; 64KB/block still fits the load window)
//  - reducer folded into G0 (one fewer block, one fewer hop consumer)
//  - NB 41 -> 32
//
// Teams (TPB=256), 3 hops (H2, H3, H4) + 7-pair PT lines to G0:
//   B: blk 0..15  h1 redundant (W1 30KB) + 16 h2 rows (16KB) -> send H2
//   C: blk 16..19 32 h3 rows (32KB); recv H2 -> send H3
//   D: blk 20..23 32 h4 rows (16KB); recv H3 -> send H4
//   G: blk 24..31 16 LSTM cells = 64 gate rows (W_ih+W_hh 64KB);
//                 g0=W_hh@hx early; recv H4 -> gates -> LSTM(16) ->
//                 7 head partials; g>0 send PT line; G0 recvs 7x7 partials,
//                 reduces, softsign, writes out.

#define NB   32
#define TPB  256
#define MAGIC 0x3A3C5A17u

#define H2_OFF 0      // 256 pairs (16 lines)
#define H3_OFF 256    // 128 pairs (8 lines)
#define H4_OFF 384    // 128 pairs (8 lines)
#define PT_OFF 512    // 8 lines; block g owns pairs [g*8 .. g*8+6]

__device__ __forceinline__ float lrelu(float v) { return v > 0.f ? v : 0.1f * v; }
__device__ __forceinline__ float sigm(float v)  { return 1.f / (1.f + __expf(-v)); }
__device__ __forceinline__ float dot4(float4 a, float4 b) {
    return a.x * b.x + a.y * b.y + a.z * b.z + a.w * b.w;
}

__device__ __forceinline__ void send(unsigned long long* p, float v) {
    unsigned lo = __float_as_uint(v);
    unsigned long long pk = (unsigned long long)lo |
                            ((unsigned long long)(lo ^ MAGIC) << 32);
    __hip_atomic_store(p, pk, __ATOMIC_RELAXED, __HIP_MEMORY_SCOPE_AGENT);
}
__device__ __forceinline__ float recv(unsigned long long* p) {
    unsigned long long pk =
        __hip_atomic_load(p, __ATOMIC_RELAXED, __HIP_MEMORY_SCOPE_AGENT);
    unsigned lo = (unsigned)pk, hi = (unsigned)(pk >> 32);
    if ((lo ^ MAGIC) == hi) return __uint_as_float(lo);
    __builtin_amdgcn_s_sleep(2);
    for (;;) {
        pk = __hip_atomic_load(p, __ATOMIC_RELAXED, __HIP_MEMORY_SCOPE_AGENT);
        lo = (unsigned)pk; hi = (unsigned)(pk >> 32);
        if ((lo ^ MAGIC) == hi) return __uint_as_float(lo);
        __builtin_amdgcn_s_sleep(8);
    }
}
__device__ __forceinline__ void touch(unsigned long long* p) {
    unsigned long long v =
        __hip_atomic_load(p, __ATOMIC_RELAXED, __HIP_MEMORY_SCOPE_AGENT);
    asm volatile("" :: "v"(v));
}

__global__ __launch_bounds__(TPB, 1) void a3c_fwd(
    const float* __restrict__ x, const float* __restrict__ hx, const float* __restrict__ cx,
    const float* __restrict__ w1, const float* __restrict__ b1,
    const float* __restrict__ w2, const float* __restrict__ b2,
    const float* __restrict__ w3, const float* __restrict__ b3,
    const float* __restrict__ w4, const float* __restrict__ b4,
    const float* __restrict__ w_ih, const float* __restrict__ b_ih,
    const float* __restrict__ w_hh, const float* __restrict__ b_hh,
    const float* __restrict__ w_critic, const float* __restrict__ b_critic,
    const float* __restrict__ w_actor, const float* __restrict__ b_actor,
    const float* __restrict__ w_actor2, const float* __restrict__ b_actor2,
    float* __restrict__ out, unsigned long long* __restrict__ wsp)
{
    const int blk = blockIdx.x, tid = threadIdx.x;

    if (blk < 16) {
        // ---- Team B: h1 (redundant, W1 first) + 16 h2 rows ----
        const int b = blk;
        if (tid == 0) touch(wsp + H2_OFF + b * 16);
        if (tid == 1) touch(wsp + H2_OFF + b * 16 + 8);

        float a1[29];
        {
            const float* w1r = w1 + tid * 29;
            #pragma unroll
            for (int j = 0; j < 29; ++j) a1[j] = w1r[j];
        }
        const float bb1 = b1[tid];

        const int r2 = b * 16 + (tid >> 4), p2 = tid & 15;
        float4 a2[4];
        {
            const float4* wp = (const float4*)(w2 + r2 * 256 + p2 * 16);
            #pragma unroll
            for (int j = 0; j < 4; ++j) a2[j] = wp[j];
        }
        const float bb2 = b2[r2];

        __shared__ __align__(16) float x_s[32];
        __shared__ __align__(16) float h1_s[256];
        if (tid < 32) x_s[tid] = (tid < 29) ? x[tid] : 0.f;
        __syncthreads();

        {
            float s = 0.f;
            #pragma unroll
            for (int j = 0; j < 29; ++j) s += a1[j] * x_s[j];
            h1_s[tid] = lrelu(s + bb1);
        }
        __syncthreads();

        {
            const float4* hp = (const float4*)(h1_s + p2 * 16);
            float s = 0.f;
            #pragma unroll
            for (int j = 0; j < 4; ++j) s += dot4(a2[j], hp[j]);
            s += __shfl_xor(s, 1); s += __shfl_xor(s, 2);
            s += __shfl_xor(s, 4); s += __shfl_xor(s, 8);
            if (p2 == 0) send(wsp + H2_OFF + r2, lrelu(s + bb2));
        }
        return;
    }

    if (blk < 20) {
        // ---- Team C: 32 h3 rows/blk ----
        const int c = blk - 16;
        if (tid < 16)       touch(wsp + H2_OFF + tid * 16);
        else if (tid < 20)  touch(wsp + H3_OFF + c * 32 + (tid - 16) * 8);

        const int r3 = c * 32 + (tid >> 3), p3 = tid & 7;
        float4 a3[8];
        {
            const float4* wp = (const float4*)(w3 + r3 * 256 + p3 * 32);
            #pragma unroll
            for (int j = 0; j < 8; ++j) a3[j] = wp[j];
        }
        const float bb3 = b3[r3];

        __shared__ __align__(16) float h2_s[256];
        h2_s[tid] = recv(wsp + H2_OFF + tid);
        __syncthreads();

        const float4* hp = (const float4*)(h2_s + p3 * 32);
        float s = 0.f;
        #pragma unroll
        for (int j = 0; j < 8; ++j) s += dot4(a3[j], hp[j]);
        s += __shfl_xor(s, 1); s += __shfl_xor(s, 2); s += __shfl_xor(s, 4);
        if (p3 == 0) send(wsp + H3_OFF + r3, lrelu(s + bb3));
        return;
    }

    if (blk < 24) {
        // ---- Team D: 32 h4 rows/blk ----
        const int d = blk - 20;
        if (tid < 8)        touch(wsp + H3_OFF + tid * 16);
        else if (tid < 12)  touch(wsp + H4_OFF + d * 32 + (tid - 8) * 8);

        const int r4 = d * 32 + (tid >> 3), p4 = tid & 7;
        float4 a4[4];
        {
            const float4* wp = (const float4*)(w4 + r4 * 128 + p4 * 16);
            #pragma unroll
            for (int j = 0; j < 4; ++j) a4[j] = wp[j];
        }
        const float bb4 = b4[r4];

        __shared__ __align__(16) float h3_s[128];
        if (tid < 128) h3_s[tid] = recv(wsp + H3_OFF + tid);
        __syncthreads();

        const float4* hp = (const float4*)(h3_s + p4 * 16);
        float s = 0.f;
        #pragma unroll
        for (int j = 0; j < 4; ++j) s += dot4(a4[j], hp[j]);
        s += __shfl_xor(s, 1); s += __shfl_xor(s, 2); s += __shfl_xor(s, 4);
        if (p4 == 0) send(wsp + H4_OFF + r4, lrelu(s + bb4));
        return;
    }

    // ---- Team G: 16 LSTM cells/blk (64 gate rows) + epilogue on G0 ----
    {
        const int g = blk - 24;                       // [0,8)
        if (tid < 8) touch(wsp + H4_OFF + tid * 16);  // recv set
        if (g > 0) { if (tid == 8) touch(wsp + PT_OFF + g * 8); }
        else       { if (tid >= 9 && tid < 16) touch(wsp + PT_OFF + (tid - 8) * 8); }

        const int r = tid >> 2, p = tid & 3;          // 64 rows x 4 lanes x 32
        const int gate = r >> 4, cell = r & 15;
        const int grow = gate * 128 + g * 16 + cell;

        float4 ah[8];
        {
            const float4* wp = (const float4*)(w_hh + grow * 128 + p * 32);
            #pragma unroll
            for (int j = 0; j < 8; ++j) ah[j] = wp[j];
        }
        float4 ai[8];
        {
            const float4* wp = (const float4*)(w_ih + grow * 128 + p * 32);
            #pragma unroll
            for (int j = 0; j < 8; ++j) ai[j] = wp[j];
        }
        const float bsum = b_ih[grow] + b_hh[grow];

        __shared__ __align__(16) float hx_s[128];
        __shared__ __align__(16) float h4_s[128];
        __shared__ __align__(16) float g_s[64];
        __shared__ __align__(16) float hn_s[16];
        __shared__ __align__(16) float hw_s[112];   // 7 heads x 16 cells
        __shared__ __align__(16) float hb_s[8];
        __shared__ __align__(16) float ps[56];      // G0: 7 heads x 8 blocks

        if (tid < 128) hx_s[tid] = hx[tid];
        float cxv = (tid < 16) ? cx[g * 16 + tid] : 0.f;
        if (tid < 112) {
            int o = tid >> 4, c = tid & 15;
            float v;
            if (o == 0)      v = w_critic[g * 16 + c];
            else if (o < 4)  v = w_actor [(o - 1) * 128 + g * 16 + c];
            else             v = w_actor2[(o - 4) * 128 + g * 16 + c];
            hw_s[tid] = v;
        }
        if (g == 0 && tid == 0) {
            hb_s[0] = b_critic[0];
            hb_s[1] = b_actor[0];  hb_s[2] = b_actor[1];  hb_s[3] = b_actor[2];
            hb_s[4] = b_actor2[0]; hb_s[5] = b_actor2[1]; hb_s[6] = b_actor2[2];
        }
        __syncthreads();

        // g0 = W_hh @ hx + biases (off critical path)
        float g0;
        {
            const float4* hp = (const float4*)(hx_s + p * 32);
            float s = 0.f;
            #pragma unroll
            for (int j = 0; j < 8; ++j) s += dot4(ah[j], hp[j]);
            s += __shfl_xor(s, 1); s += __shfl_xor(s, 2);
            g0 = s + bsum;
        }

        if (tid < 128) h4_s[tid] = recv(wsp + H4_OFF + tid);
        __syncthreads();

        { // gates for 64 rows
            const float4* hp = (const float4*)(h4_s + p * 32);
            float s = 0.f;
            #pragma unroll
            for (int j = 0; j < 8; ++j) s += dot4(ai[j], hp[j]);
            s += __shfl_xor(s, 1); s += __shfl_xor(s, 2);
            if (p == 0) g_s[r] = g0 + s;   // r = gate*16 + cell
        }
        __syncthreads();

        if (tid < 16) {   // LSTM elementwise, 16 cells
            float ig = g_s[tid];
            float fg = g_s[16 + tid];
            float gg = g_s[32 + tid];
            float og = g_s[48 + tid];
            float c  = sigm(fg) * cxv + sigm(ig) * tanhf(gg);
            hn_s[tid] = sigm(og) * tanhf(c);
        }
        __syncthreads();

        if (tid < 7) {    // 7 head partials over this block's 16 cells
            const float* wc = hw_s + tid * 16;
            float s = 0.f;
            #pragma unroll
            for (int j = 0; j < 16; ++j) s += wc[j] * hn_s[j];
            if (g > 0) send(wsp + PT_OFF + g * 8 + tid, s);
            else       ps[tid * 8] = s + hb_s[tid];
        }

        if (g == 0) {
            // recv 7 blocks x 7 heads of partials
            if (tid < 56) {
                const int gg = (tid >> 3) + 1, h = tid & 7;
                if (h < 7) ps[h * 8 + gg] = recv(wsp + PT_OFF + gg * 8 + h);
            }
            __syncthreads();
            if (tid < 7) {
                const float* row = ps + tid * 8;
                float s = row[0] + row[1] + row[2] + row[3]
                        + row[4] + row[5] + row[6] + row[7];
                if (tid >= 1 && tid <= 3) s = s / (1.f + fabsf(s));
                out[tid] = s;
            }
        }
    }
}

extern "C" void kernel_launch(void* const* d_in, const int* in_sizes, int n_in,
                              void* d_out, int out_size, void* d_ws, size_t ws_size,
                              hipStream_t stream) {
    const float* x        = (const float*)d_in[0];
    const float* hx       = (const float*)d_in[1];
    const float* cx       = (const float*)d_in[2];
    const float* w1       = (const float*)d_in[3];
    const float* b1       = (const float*)d_in[4];
    const float* w2       = (const float*)d_in[5];
    const float* b2       = (const float*)d_in[6];
    const float* w3       = (const float*)d_in[7];
    const float* b3       = (const float*)d_in[8];
    const float* w4       = (const float*)d_in[9];
    const float* b4       = (const float*)d_in[10];
    const float* w_ih     = (const float*)d_in[11];
    const float* b_ih     = (const float*)d_in[12];
    const float* w_hh     = (const float*)d_in[13];
    const float* b_hh     = (const float*)d_in[14];
    const float* w_critic = (const float*)d_in[15];
    const float* b_critic = (const float*)d_in[16];
    const float* w_actor  = (const float*)d_in[17];
    const float* b_actor  = (const float*)d_in[18];
    const float* w_actor2 = (const float*)d_in[19];
    const float* b_actor2 = (const float*)d_in[20];
    float* out = (float*)d_out;
    unsigned long long* wsp = (unsigned long long*)d_ws;

    a3c_fwd<<<NB, TPB, 0, stream>>>(x, hx, cx, w1, b1, w2, b2, w3, b3, w4, b4,
                                    w_ih, b_ih, w_hh, b_hh,
                                    w_critic, b_critic, w_actor, b_actor,
                                    w_actor2, b_actor2, out, wsp);
}